// Round 17
// baseline (908.809 us; speedup 1.0000x reference)
//
#include <hip/hip_runtime.h>
#include <hip/hip_bf16.h>

// ---------------------------------------------------------------------------
// InvSlotAttentionGuide: CNN encoder -> pos embed -> MLP -> slot attention
// with MESH-Sinkhorn (manual reverse-mode through 5 sinkhorn iters).
// R34: (a) conv3/conv4 part kernels re-tiled to 8x16 spatial tiles ->
// grid (8,4,64) = 2048 blocks = 8 blocks/CU = 8 waves/SIMD (R33 was 4).
// Pure thread remap: per-output ci/ky/kx order unchanged (2 oc x 4 px per
// thread, float2 weight reads). (b) conv4's fuse folded into token_kernel
// (inline 4-partial sum + bias + relu, same association as fuse4) -- one
// fewer launch, no act4 round-trip. sa = R25-exact (322us measured; all
// parallelization axes measured-closed). R23 conv prefetch retained.
// R33 measured 867us (conv ci-split -80us); R31 942; R25 956.
// ---------------------------------------------------------------------------

#define LN_EPS 1e-5f
#define SEPS 1e-8f
#define LN8 2.0794415416798357f

__device__ inline float ldf(float x) { return x; }
__device__ inline float ldf(__hip_bfloat16 x) { return __bfloat162float(x); }
__device__ inline void stf(float* p, float v) { *p = v; }
__device__ inline void stf(__hip_bfloat16* p, float v) { *p = __float2bfloat16(v); }

__device__ inline float wmaxall(float v) {
#pragma unroll
  for (int o = 32; o; o >>= 1) v = fmaxf(v, __shfl_down(v, o));
  return __shfl(v, 0);
}
__device__ inline float wsumall(float v) {
#pragma unroll
  for (int o = 32; o; o >>= 1) v += __shfl_down(v, o);
  return __shfl(v, 0);
}
__device__ inline int wsumi(int v) {
#pragma unroll
  for (int o = 32; o; o >>= 1) v += __shfl_down(v, o);
  return __shfl(v, 0);
}
__device__ inline float fast_sigmoid(float x) { return 1.f / (1.f + __expf(-x)); }
__device__ inline float fast_tanh(float x) { return 1.f - 2.f / (__expf(2.f * x) + 1.f); }

struct CvtArgs {
  const void* src[39];
  long off[40];
};

// R32: sniff fused — first wave computes the bf16-vs-f32 flag from src[0].
__global__ __launch_bounds__(256) void convert_kernel(CvtArgs a,
                                                      float* __restrict__ dst, long total) {
  __shared__ int sFlag;
  {
    const unsigned int* img = (const unsigned int*)a.src[0];
    if (threadIdx.x < 64) {
      int cnt = 0;
      for (int i = threadIdx.x; i < 512; i += 64) {
        unsigned lo = img[i] & 0xFFFFu;
        int e = (int)((lo >> 7) & 0xFFu);
        cnt += (e >= 96 && e <= 140) ? 1 : 0;
      }
      cnt = wsumi(cnt);
      if (threadIdx.x == 0) sFlag = (cnt >= 300) ? 1 : 0;
    }
    __syncthreads();
  }
  const int isbf = sFlag;
  for (long g = (long)blockIdx.x * 256 + threadIdx.x; g < total; g += (long)gridDim.x * 256) {
    int lo = 0, hi = 38;
    while (lo < hi) {
      int mid = (lo + hi + 1) >> 1;
      if (a.off[mid] <= g) lo = mid; else hi = mid - 1;
    }
    long li = g - a.off[lo];
    float v;
    if (isbf) v = __bfloat162float(((const __hip_bfloat16*)a.src[lo])[li]);
    else      v = ((const float*)a.src[lo])[li];
    dst[g] = v;
  }
}

// ---------------------------------------------------------------------------
struct TwArgs {
  long soff[9]; long doff[9]; int R[9]; int C[9];
};

__global__ __launch_bounds__(256) void transw_kernel(const float* __restrict__ cvt,
                                                     float* __restrict__ tws, TwArgs a) {
  int m = blockIdx.x;
  const float* S = cvt + a.soff[m];
  float* D = tws + a.doff[m];
  int R = a.R[m], C = a.C[m];
  for (int idx = threadIdx.x; idx < R * C; idx += 256) {
    int i = idx / C, j = idx - i * C;
    D[j * R + i] = S[idx];
  }
}

// ---------------------------------------------------------------------------
// Direct 5x5 conv + bias + relu: 16x16 tile x 16 oc per block.
// R23: double-buffered staging. Used by conv1 (S=1) and conv2 (S=2).
// ---------------------------------------------------------------------------
template <int S, typename TIN, typename TOUT>
__global__ __launch_bounds__(256) void conv5x5(
    const TIN* __restrict__ in, const float* __restrict__ wgt,
    const float* __restrict__ bias, TOUT* __restrict__ out,
    int Cin, int H, int W, int Ho, int Wo, int Cout, int tilesX) {
  constexpr int P = 15 * S + 5;
  constexpr int PP = (S == 1) ? 20 : 40;
  constexpr int NCH = (S == 1) ? 2 : 3;
  constexpr int NP = (P * P + 255) / 256;
  __shared__ __align__(16) float patch[P * PP];
  __shared__ float wt16[25 * 16];
  const int b = blockIdx.z;
  const int ocg = blockIdx.y * 16;
  const int ty0 = (blockIdx.x / tilesX) * 16, tx0 = (blockIdx.x % tilesX) * 16;
  const int og = threadIdx.x >> 6;
  const int r = (threadIdx.x >> 2) & 15;
  const int rx = threadIdx.x & 3;
  const int iy0 = ty0 * S - 2, ix0 = tx0 * S - 2;
  const long HW = (long)H * W;

  int toff[NP], soff[NP];
#pragma unroll
  for (int q = 0; q < NP; q++) {
    int idx = threadIdx.x + 256 * q;
    toff[q] = -1;
    soff[q] = -1;
    if (idx < P * P) {
      int py = idx / P, px = idx - py * P;
      int iy = iy0 + py, ix = ix0 + px;
      int pxs = (S == 2) ? (px ^ (((py >> 1) & 1) << 2)) : px;
      toff[q] = py * PP + pxs;
      if (iy >= 0 && iy < H && ix >= 0 && ix < W) soff[q] = iy * W + ix;
    }
  }
  int wsrc[2];
#pragma unroll
  for (int q = 0; q < 2; q++) {
    int idx = threadIdx.x + 256 * q;
    wsrc[q] = (idx < 400) ? (((ocg + (idx & 15)) * Cin) * 25 + (idx >> 4)) : -1;
  }

  float acc[4][4];
#pragma unroll
  for (int p = 0; p < 4; p++)
#pragma unroll
    for (int j = 0; j < 4; j++) acc[p][j] = 0.f;

  float pr[NP], wr[2];
  {
    const TIN* inp = in + (long)b * Cin * HW;
#pragma unroll
    for (int q = 0; q < NP; q++) pr[q] = (soff[q] >= 0) ? ldf(inp[soff[q]]) : 0.f;
#pragma unroll
    for (int q = 0; q < 2; q++) wr[q] = (wsrc[q] >= 0) ? wgt[wsrc[q]] : 0.f;
  }

  for (int ci = 0; ci < Cin; ++ci) {
    __syncthreads();
#pragma unroll
    for (int q = 0; q < NP; q++)
      if (toff[q] >= 0) patch[toff[q]] = pr[q];
#pragma unroll
    for (int q = 0; q < 2; q++) {
      int idx = threadIdx.x + 256 * q;
      if (idx < 400) wt16[idx] = wr[q];
    }
    __syncthreads();
    if (ci + 1 < Cin) {
      const TIN* inp = in + ((long)b * Cin + ci + 1) * HW;
#pragma unroll
      for (int q = 0; q < NP; q++) pr[q] = (soff[q] >= 0) ? ldf(inp[soff[q]]) : 0.f;
#pragma unroll
      for (int q = 0; q < 2; q++)
        if (wsrc[q] >= 0) wr[q] = wgt[wsrc[q] + (ci + 1) * 25];
    }
#pragma unroll
    for (int ky = 0; ky < 5; ky++) {
      float win[4 * NCH];
      const int row = r * S + ky;
      const float* rb = &patch[row * PP];
      if constexpr (S == 2) {
        const int sw = (row >> 1) & 1;
#pragma unroll
        for (int c = 0; c < NCH; c++) {
          const int g = rx * 2 + c;
          float4 t4 = *(const float4*)(rb + ((g ^ sw) << 2));
          win[4 * c + 0] = t4.x;
          win[4 * c + 1] = t4.y;
          win[4 * c + 2] = t4.z;
          win[4 * c + 3] = t4.w;
        }
      } else {
        const float* bp = rb + rx * 4;
#pragma unroll
        for (int c = 0; c < NCH; c++) {
          float4 t4 = *(const float4*)(bp + 4 * c);
          win[4 * c + 0] = t4.x;
          win[4 * c + 1] = t4.y;
          win[4 * c + 2] = t4.z;
          win[4 * c + 3] = t4.w;
        }
      }
#pragma unroll
      for (int kx = 0; kx < 5; kx++) {
        const float4 wv = *(const float4*)&wt16[(ky * 5 + kx) * 16 + og * 4];
#pragma unroll
        for (int p = 0; p < 4; p++) {
          float iv = win[p * S + kx];
          acc[p][0] += iv * wv.x;
          acc[p][1] += iv * wv.y;
          acc[p][2] += iv * wv.z;
          acc[p][3] += iv * wv.w;
        }
      }
    }
  }
  const int oy = ty0 + r, ox0 = tx0 + rx * 4;
#pragma unroll
  for (int j = 0; j < 4; j++) {
    int oc = ocg + og * 4 + j;
    float bs = bias[oc];
    TOUT* op = &out[(((long)b * Cout + oc) * Ho + oy) * Wo + ox0];
#pragma unroll
    for (int p = 0; p < 4; p++) stf(&op[p], fmaxf(acc[p][j] + bs, 0.f));
  }
}

// ---------------------------------------------------------------------------
// R34: ci-split partial conv, 8x16 spatial tiles. blockIdx.z = b*4+quarter
// (16 ci each); blockIdx.x covers (Ho/8)x(Wo/16) tiles -> 2048 blocks =
// 8 blocks/CU = 8 waves/SIMD. Thread map: og=tid>>5 (8 groups x 2 oc),
// r=(tid>>2)&7, rx=tid&3 (4 px). Per-output ci/ky/kx order identical.
// ---------------------------------------------------------------------------
template <int S, typename TIN>
__global__ __launch_bounds__(256) void conv5x5_part(
    const TIN* __restrict__ in, const float* __restrict__ wgt,
    float* __restrict__ pout,
    int Cin, int H, int W, int Ho, int Wo, int Cout, int tilesX) {
  constexpr int PR = 7 * S + 5;        // rows for 8-row tile
  constexpr int PC = 15 * S + 5;       // cols for 16-col tile
  constexpr int PP = (S == 1) ? 20 : 40;
  constexpr int NCH = (S == 1) ? 2 : 3;
  constexpr int NP = (PR * PC + 255) / 256;
  __shared__ __align__(16) float patch[PR * PP];
  __shared__ float wt16[25 * 16];
  const int zz = blockIdx.z;
  const int qh = zz & 3;             // ci quarter
  const int b = zz >> 2;
  const int nci = Cin >> 2;          // 16
  const int c0 = qh * nci;
  const int ocg = blockIdx.y * 16;
  const int ty0 = (blockIdx.x / tilesX) * 8, tx0 = (blockIdx.x % tilesX) * 16;
  const int og = threadIdx.x >> 5;         // 0..7 -> oc pair
  const int r = (threadIdx.x >> 2) & 7;    // tile row 0..7
  const int rx = threadIdx.x & 3;          // 4-px col group
  const int iy0 = ty0 * S - 2, ix0 = tx0 * S - 2;
  const long HW = (long)H * W;

  int toff[NP], soff[NP];
#pragma unroll
  for (int q = 0; q < NP; q++) {
    int idx = threadIdx.x + 256 * q;
    toff[q] = -1;
    soff[q] = -1;
    if (idx < PR * PC) {
      int py = idx / PC, px = idx - py * PC;
      int iy = iy0 + py, ix = ix0 + px;
      int pxs = (S == 2) ? (px ^ (((py >> 1) & 1) << 2)) : px;
      toff[q] = py * PP + pxs;
      if (iy >= 0 && iy < H && ix >= 0 && ix < W) soff[q] = iy * W + ix;
    }
  }
  int wsrc[2];
#pragma unroll
  for (int q = 0; q < 2; q++) {
    int idx = threadIdx.x + 256 * q;
    wsrc[q] = (idx < 400) ? (((ocg + (idx & 15)) * Cin) * 25 + (idx >> 4)) : -1;
  }

  float acc[4][2];
#pragma unroll
  for (int p = 0; p < 4; p++) {
    acc[p][0] = 0.f;
    acc[p][1] = 0.f;
  }

  float pr[NP], wr[2];
  {
    const TIN* inp = in + ((long)b * Cin + c0) * HW;
#pragma unroll
    for (int q = 0; q < NP; q++) pr[q] = (soff[q] >= 0) ? ldf(inp[soff[q]]) : 0.f;
#pragma unroll
    for (int q = 0; q < 2; q++) wr[q] = (wsrc[q] >= 0) ? wgt[wsrc[q] + c0 * 25] : 0.f;
  }

  const int cEnd = c0 + nci;
  for (int ci = c0; ci < cEnd; ++ci) {
    __syncthreads();
#pragma unroll
    for (int q = 0; q < NP; q++)
      if (toff[q] >= 0) patch[toff[q]] = pr[q];
#pragma unroll
    for (int q = 0; q < 2; q++) {
      int idx = threadIdx.x + 256 * q;
      if (idx < 400) wt16[idx] = wr[q];
    }
    __syncthreads();
    if (ci + 1 < cEnd) {
      const TIN* inp = in + ((long)b * Cin + ci + 1) * HW;
#pragma unroll
      for (int q = 0; q < NP; q++) pr[q] = (soff[q] >= 0) ? ldf(inp[soff[q]]) : 0.f;
#pragma unroll
      for (int q = 0; q < 2; q++)
        if (wsrc[q] >= 0) wr[q] = wgt[wsrc[q] + (ci + 1) * 25];
    }
#pragma unroll
    for (int ky = 0; ky < 5; ky++) {
      float win[4 * NCH];
      const int row = r * S + ky;
      const float* rb = &patch[row * PP];
      if constexpr (S == 2) {
        const int sw = (row >> 1) & 1;
#pragma unroll
        for (int c = 0; c < NCH; c++) {
          const int g = rx * 2 + c;
          float4 t4 = *(const float4*)(rb + ((g ^ sw) << 2));
          win[4 * c + 0] = t4.x;
          win[4 * c + 1] = t4.y;
          win[4 * c + 2] = t4.z;
          win[4 * c + 3] = t4.w;
        }
      } else {
        const float* bp = rb + rx * 4;
#pragma unroll
        for (int c = 0; c < NCH; c++) {
          float4 t4 = *(const float4*)(bp + 4 * c);
          win[4 * c + 0] = t4.x;
          win[4 * c + 1] = t4.y;
          win[4 * c + 2] = t4.z;
          win[4 * c + 3] = t4.w;
        }
      }
#pragma unroll
      for (int kx = 0; kx < 5; kx++) {
        const float* wp = &wt16[(ky * 5 + kx) * 16 + og * 2];
        float w0 = wp[0], w1 = wp[1];
#pragma unroll
        for (int p = 0; p < 4; p++) {
          float iv = win[p * S + kx];
          acc[p][0] += iv * w0;
          acc[p][1] += iv * w1;
        }
      }
    }
  }
  const int oy = ty0 + r, ox0 = tx0 + rx * 4;
#pragma unroll
  for (int j = 0; j < 2; j++) {
    int oc = ocg + og * 2 + j;
    float* op = &pout[((((long)qh * 16 + b) * Cout + oc) * Ho + oy) * Wo + ox0];
#pragma unroll
    for (int p = 0; p < 4; p++) op[p] = acc[p][j];
  }
}

// relu(p0+p1+p2+p3+bias) -> f32 output. qtr = elements per quarter.
__global__ __launch_bounds__(256) void fuse4_kernel(
    const float* __restrict__ pin, const float* __restrict__ bias,
    float* __restrict__ outF, int HoWo, int Cout, long qtr) {
  for (long i = (long)blockIdx.x * 256 + threadIdx.x; i < qtr;
       i += (long)gridDim.x * 256) {
    int oc = (int)((i / HoWo) % Cout);
    float v = ((pin[i] + pin[i + qtr]) + pin[i + 2 * qtr]) + pin[i + 3 * qtr];
    outF[i] = fmaxf(v + bias[oc], 0.f);
  }
}

// ---------------------------------------------------------------------------
// Per-token pipeline, R34: 256 threads = 4 waves = 4 tokens per block,
// weights in LDS (R32). conv4's fuse folded in: reads the 4 ci-partials,
// sums with fuse4's association, + bias + relu (act4 never materialized).
// ---------------------------------------------------------------------------
__global__ __launch_bounds__(256) void token_kernel(
    const float* __restrict__ parts, const float* __restrict__ cb4,
    const float* __restrict__ pos_w, const float* __restrict__ pos_b,
    const float* __restrict__ mlp1T, const float* __restrict__ mlp1_b,
    const float* __restrict__ mlp2T, const float* __restrict__ mlp2_b,
    const float* __restrict__ lnin_w, const float* __restrict__ lnin_b,
    const float* __restrict__ wkT, const float* __restrict__ wvT,
    const float* __restrict__ mwi_w, const float* __restrict__ mwi_b,
    float* __restrict__ knT_out, float* __restrict__ v_out, float* __restrict__ lg_out) {
  const int wq = threadIdx.x >> 6, i = threadIdx.x & 63;
  const int t = blockIdx.x * 4 + wq;
  const int b = t >> 10, nn = t & 1023;
  const int h = nn >> 5, w = nn & 31;
  __shared__ float sM1[4096], sM2[4096], sWk[4096], sWv[4096];
  __shared__ float f[4][64], h1[4][64], inp[4][64];
  for (int idx = threadIdx.x; idx < 4096; idx += 256) {
    sM1[idx] = mlp1T[idx];
    sM2[idx] = mlp2T[idx];
    sWk[idx] = wkT[idx];
    sWv[idx] = wvT[idx];
  }
  {
    float gh = h * (1.f / 31.f), gw = w * (1.f / 31.f);
    float e = gh * pos_w[i * 4 + 0] + gw * pos_w[i * 4 + 1] +
              (1.f - gh) * pos_w[i * 4 + 2] + (1.f - gw) * pos_w[i * 4 + 3] + pos_b[i];
    const long base = ((long)b * 64 + i) * 1024 + nn;
    const long q = 16L * 64 * 1024;
    float v = ((parts[base] + parts[base + q]) + parts[base + 2 * q]) + parts[base + 3 * q];
    f[wq][i] = fmaxf(v + cb4[i], 0.f) + e;
  }
  __syncthreads();
  float acc = 0.f;
  for (int j = 0; j < 64; j++) acc += f[wq][j] * sM1[j * 64 + i];
  h1[wq][i] = fmaxf(acc + mlp1_b[i], 0.f);
  __syncthreads();
  acc = 0.f;
  for (int j = 0; j < 64; j++) acc += h1[wq][j] * sM2[j * 64 + i];
  float x = acc + mlp2_b[i];
  float m = wsumall(x) * (1.f / 64.f);
  float d0 = x - m;
  float var = wsumall(d0 * d0) * (1.f / 64.f);
  float xin = d0 * rsqrtf(var + LN_EPS) * lnin_w[i] + lnin_b[i];
  inp[wq][i] = xin;
  __syncthreads();
  float kv = 0.f, vv = 0.f;
  for (int j = 0; j < 64; j++) {
    float ij = inp[wq][j];
    kv += ij * sWk[j * 64 + i];
    vv += ij * sWv[j * 64 + i];
  }
  float ss = wsumall(kv * kv);
  knT_out[(long)b * 65536 + i * 1024 + nn] = kv / fmaxf(sqrtf(ss), 1e-12f);
  v_out[(long)t * 64 + i] = vv;
  float lg = wsumall(xin * mwi_w[i]);
  if (i == 0) lg_out[t] = lg + mwi_b[0];
}

// ---------------------------------------------------------------------------
// Slot-attention loop (R25-exact): 512 threads = 8 waves, exp-factored
// Sinkhorn. 2 barriers/step, per-wave column reduce, lane-0 finish.
// ---------------------------------------------------------------------------
__global__ __launch_bounds__(512) void sa_kernel(
    const float* __restrict__ knT_g, const float* __restrict__ v_g,
    const float* __restrict__ la_g, const float* __restrict__ noise,
    const float* __restrict__ mu_w, const float* __restrict__ sg_w,
    const float* __restrict__ lnsl_w, const float* __restrict__ lnsl_b,
    const float* __restrict__ mws_w, const float* __restrict__ mws_b,
    const float* __restrict__ wqT,
    const float* __restrict__ wihT, const float* __restrict__ whhT,
    const float* __restrict__ bih, const float* __restrict__ bhh,
    const float* __restrict__ lnff_w, const float* __restrict__ lnff_b,
    const float* __restrict__ fc1T, const float* __restrict__ fc1_b,
    const float* __restrict__ fc2T, const float* __restrict__ fc2_b,
    float* __restrict__ out) {
  const int b = blockIdx.x, tid = threadIdx.x;
  const int wv = tid >> 6, ln = tid & 63;

  __shared__ float sCt[8192];           // C, then pi
  __shared__ float sEc[8192];           // exp(-C)
  __shared__ float sLa[1024], sELa[1024], sHid[1024];
  __shared__ float sPart[512 * 9];      // per-thread partials, 9-stride (2-way free)
  __shared__ float sVh[48], sV[8], sEsv[8], sGv[8], sLb[8], sBm[8];
  __shared__ float sC1[8], sEvh[8];
  __shared__ float sSlots[512], sNorm[512], sQn[512], sUpd[512];

  const float* knt = knT_g + (long)b * 65536;
  const float* vf = v_g + (long)b * 65536;
  float sInvH[5][2];   // 1/S per fwd step per token (replaces u_hist)
  float gPr[2][8];
  float gInit[2];

  {
    int dd = tid & 63;
    sSlots[tid] = mu_w[dd] + (fabsf(sg_w[dd]) + SEPS) * noise[(long)b * 512 + tid];
  }
  for (int n = tid; n < 1024; n += 512) sLa[n] = la_g[b * 1024 + n];
  __syncthreads();
  {  // fused la: sLa <- raw - LSE + ln8 ; also eLa = exp(sLa)
    float a0 = sLa[tid], a1 = sLa[tid + 512];
    float m0 = wmaxall(fmaxf(a0, a1));
    if (ln == 0) sBm[wv] = m0;
    __syncthreads();
    float M = sBm[0];
#pragma unroll
    for (int s = 1; s < 8; s++) M = fmaxf(M, sBm[s]);
    float e0 = wsumall(__expf(a0 - M) + __expf(a1 - M));
    if (ln == 0) sGv[wv] = e0;
    __syncthreads();
    float SS = 0.f;
#pragma unroll
    for (int s = 0; s < 8; s++) SS += sGv[s];
    float lse = M + __logf(SS);
    float l0 = a0 - lse + LN8, l1 = a1 - lse + LN8;
    sLa[tid] = l0;
    sLa[tid + 512] = l1;
    sELa[tid] = __expf(l0);
    sELa[tid + 512] = __expf(l1);
  }
  __syncthreads();

  for (int it = 0; it < 3; ++it) {
    {
      float x = sSlots[wv * 64 + ln];
      float m = wsumall(x) * (1.f / 64.f);
      float d0 = x - m;
      float var = wsumall(d0 * d0) * (1.f / 64.f);
      float xn = d0 * rsqrtf(var + LN_EPS) * lnsl_w[ln] + lnsl_b[ln];
      sNorm[wv * 64 + ln] = xn;
      float bmv = wsumall(xn * mws_w[ln]);
      if (ln == 0) sBm[wv] = bmv + mws_b[0];
    }
    __syncthreads();
    if (tid == 0) {
      float mx = -1e30f;
      for (int s = 0; s < 8; s++) mx = fmaxf(mx, sBm[s]);
      float ss = 0.f;
      for (int s = 0; s < 8; s++) ss += __expf(sBm[s] - mx);
      float lse = mx + __logf(ss);
      for (int s = 0; s < 8; s++) sLb[s] = sBm[s] - lse + LN8;
    }
    {
      float acc = 0.f;
      for (int j = 0; j < 64; j++) acc += sNorm[wv * 64 + j] * wqT[j * 64 + ln];
      sQn[tid] = acc;
    }
    __syncthreads();
    {
      float qv = sQn[wv * 64 + ln];
      float ss = wsumall(qv * qv);
      sQn[wv * 64 + ln] = qv / fmaxf(sqrtf(ss), 1e-12f);
    }
    if (tid < 8) {
      sV[tid] = 0.f;
      sEsv[tid] = 1.f;
    }
    __syncthreads();

#pragma unroll
    for (int k = 0; k < 2; k++) {  // C = 1 - kn.qn ; eC = exp(-C)
      int n = tid + 512 * k;
      float acc[8];
#pragma unroll
      for (int s = 0; s < 8; s++) acc[s] = 0.f;
      for (int j = 0; j < 64; j++) {
        float kvv = knt[j * 1024 + n];
#pragma unroll
        for (int s = 0; s < 8; s++) acc[s] += kvv * sQn[s * 64 + j];
      }
#pragma unroll
      for (int s = 0; s < 8; s++) {
        float c = 1.f - acc[s];
        sCt[s * 1024 + n] = c;
        sEc[s * 1024 + n] = __expf(-c);
      }
    }
    __syncthreads();

    for (int m = 0; m < 4; m++) {
#pragma unroll
      for (int t = 1; t <= 5; t++) {  // fwd sinkhorn, factored
        if (t == 1 && tid < 8) sVh[tid] = sV[tid];
        float esv_r[8], part[8];
#pragma unroll
        for (int s = 0; s < 8; s++) { esv_r[s] = sEsv[s]; part[s] = 0.f; }
#pragma unroll
        for (int k = 0; k < 2; k++) {
          int n = tid + 512 * k;
          float ec[8], S = 0.f;
#pragma unroll
          for (int s = 0; s < 8; s++) {
            ec[s] = sEc[s * 1024 + n];
            S += esv_r[s] * ec[s];
          }
          float inv = 1.f / S;
          sInvH[t - 1][k] = inv;
          float w = sELa[n] * inv;
#pragma unroll
          for (int s = 0; s < 8; s++) part[s] += w * ec[s];
        }
#pragma unroll
        for (int s = 0; s < 8; s++) sPart[tid * 9 + s] = part[s];
        __syncthreads();
        {
          int s = wv;
          float acc = 0.f;
#pragma unroll
          for (int q = 0; q < 8; q++) acc += sPart[(ln + 64 * q) * 9 + s];
          acc = wsumall(acc);
          if (ln == 0) {
            float vs = sLb[s] - __logf(acc);   // ms cancels exactly
            sV[s] = vs;
            sVh[t * 8 + s] = vs;
            sEsv[s] = __expf(vs);
          }
        }
        __syncthreads();
      }
      {  // entropy gradient seed: pi = (eLa/S5)*esv*eC, col sum accumulated
        float esv_r[8], part[8];
#pragma unroll
        for (int s = 0; s < 8; s++) { esv_r[s] = sEsv[s]; part[s] = 0.f; }
#pragma unroll
        for (int k = 0; k < 2; k++) {
          int n = tid + 512 * k;
          float al = sELa[n] * sInvH[4][k];
          float gul = 0.f;
#pragma unroll
          for (int s = 0; s < 8; s++) {
            float pi = al * esv_r[s] * sEc[s * 1024 + n];
            float gl = -(__logf(pi + SEPS) + pi / (pi + SEPS)) * pi * (1.f / 16.f);
            gPr[k][s] = gl;
            gul += gl;
            part[s] += gl;
          }
          gInit[k] = gul;
        }
#pragma unroll
        for (int s = 0; s < 8; s++) sPart[tid * 9 + s] = part[s];
        __syncthreads();
        {
          int s = wv;
          float acc = 0.f;
#pragma unroll
          for (int q = 0; q < 8; q++) acc += sPart[(ln + 64 * q) * 9 + s];
          acc = wsumall(acc);
          if (ln == 0) {
            sGv[s] = acc;
            sC1[s] = acc * __expf(sVh[40 + s] - sLb[s]);  // for t=5
            sEvh[s] = __expf(sVh[32 + s]);
          }
        }
        __syncthreads();
      }
#pragma unroll
      for (int t = 5; t >= 1; t--) {  // bwd, factored
        float c1_r[8], evh_r[8], part[8];
#pragma unroll
        for (int s = 0; s < 8; s++) {
          c1_r[s] = sC1[s];
          evh_r[s] = sEvh[s];
          part[s] = 0.f;
        }
#pragma unroll
        for (int k = 0; k < 2; k++) {
          int n = tid + 512 * k;
          float inv = sInvH[t - 1][k];
          float al = sELa[n] * inv;
          float gul = (t == 5) ? gInit[k] : 0.f;
          float ec[8];
#pragma unroll
          for (int s = 0; s < 8; s++) {
            ec[s] = sEc[s * 1024 + n];
            float t2 = al * c1_r[s] * ec[s];
            gPr[k][s] -= t2;
            gul -= t2;
          }
          float bv = gul * inv;   // exp(-rowlse) = 1/S_t
#pragma unroll
          for (int s = 0; s < 8; s++) {
            float pe = bv * ec[s];
            gPr[k][s] -= pe * evh_r[s];
            part[s] += pe;
          }
          if (t == 1) {
#pragma unroll
            for (int s = 0; s < 8; s++) {
              float cn = sCt[s * 1024 + n] + gPr[k][s];
              sCt[s * 1024 + n] = cn;
              sEc[s * 1024 + n] = __expf(-cn);
            }
          }
        }
        if (t > 1) {
#pragma unroll
          for (int s = 0; s < 8; s++) sPart[tid * 9 + s] = part[s];
        }
        if (t == 1 && tid < 8) {
          float vs = sVh[40 + tid];
          sV[tid] = vs;
          sEsv[tid] = __expf(vs);
        }
        __syncthreads();
        if (t > 1) {
          int s = wv;
          float acc = 0.f;
#pragma unroll
          for (int q = 0; q < 8; q++) acc += sPart[(ln + 64 * q) * 9 + s];
          acc = wsumall(acc);
          if (ln == 0) {
            float gn = -sEvh[s] * acc;
            sGv[s] = gn;
            sC1[s] = gn * __expf(sVh[(t - 1) * 8 + s] - sLb[s]);  // next step t-1
            sEvh[s] = __expf(sVh[(t - 2) * 8 + s]);
          }
          __syncthreads();
        }
      }
    }

    float invF[2];
    for (int t = 0; t < 5; t++) {  // final warm-start sinkhorn, factored
      float esv_r[8], part[8];
#pragma unroll
      for (int s = 0; s < 8; s++) { esv_r[s] = sEsv[s]; part[s] = 0.f; }
#pragma unroll
      for (int k = 0; k < 2; k++) {
        int n = tid + 512 * k;
        float ec[8], S = 0.f;
#pragma unroll
        for (int s = 0; s < 8; s++) {
          ec[s] = sEc[s * 1024 + n];
          S += esv_r[s] * ec[s];
        }
        float inv = 1.f / S;
        invF[k] = inv;
        float w = sELa[n] * inv;
#pragma unroll
        for (int s = 0; s < 8; s++) part[s] += w * ec[s];
      }
#pragma unroll
      for (int s = 0; s < 8; s++) sPart[tid * 9 + s] = part[s];
      __syncthreads();
      {
        int s = wv;
        float acc = 0.f;
#pragma unroll
        for (int q = 0; q < 8; q++) acc += sPart[(ln + 64 * q) * 9 + s];
        acc = wsumall(acc);
        if (ln == 0) {
          float vs = sLb[s] - __logf(acc);
          sV[s] = vs;
          sEsv[s] = __expf(vs);
        }
      }
      __syncthreads();
    }
    {  // pi = (eLa/S5) * esv * eC  — zero exp
      float esv_r[8];
#pragma unroll
      for (int s = 0; s < 8; s++) esv_r[s] = sEsv[s];
#pragma unroll
      for (int k = 0; k < 2; k++) {
        int n = tid + 512 * k;
        float al = sELa[n] * invF[k];
#pragma unroll
        for (int s = 0; s < 8; s++)
          sCt[s * 1024 + n] = al * esv_r[s] * sEc[s * 1024 + n];
      }
    }
    __syncthreads();
    if (it == 2) {
      for (int o = tid; o < 8192; o += 512) out[8192 + (long)b * 8192 + o] = sCt[o];
    }
    {
      int s = tid >> 6, dd = tid & 63;
      float acc = 0.f;
      for (int n = 0; n < 1024; n++) acc += sCt[s * 1024 + n] * vf[n * 64 + dd];
      sUpd[tid] = acc;
    }
    __syncthreads();
    float newslot;
    {
      int s = tid >> 6, i = tid & 63;
      const float* x = &sUpd[s * 64];
      const float* h = &sSlots[s * 64];
      float gir = 0, giz = 0, gin = 0, ghr = 0, ghz = 0, ghn = 0;
      for (int j = 0; j < 64; j++) {
        float xv = x[j], hv = h[j];
        gir += xv * wihT[j * 192 + i];
        giz += xv * wihT[j * 192 + 64 + i];
        gin += xv * wihT[j * 192 + 128 + i];
        ghr += hv * whhT[j * 192 + i];
        ghz += hv * whhT[j * 192 + 64 + i];
        ghn += hv * whhT[j * 192 + 128 + i];
      }
      gir += bih[i]; giz += bih[64 + i]; gin += bih[128 + i];
      ghr += bhh[i]; ghz += bhh[64 + i]; ghn += bhh[128 + i];
      float r = fast_sigmoid(gir + ghr);
      float z = fast_sigmoid(giz + ghz);
      float nn = fast_tanh(gin + r * ghn);
      newslot = (1.f - z) * nn + z * h[i];
    }
    __syncthreads();
    sSlots[tid] = newslot;
    __syncthreads();
    {
      float x = sSlots[wv * 64 + ln];
      float m = wsumall(x) * (1.f / 64.f);
      float d0 = x - m;
      float var = wsumall(d0 * d0) * (1.f / 64.f);
      sNorm[wv * 64 + ln] = d0 * rsqrtf(var + LN_EPS) * lnff_w[ln] + lnff_b[ln];
    }
    __syncthreads();
    for (int o = tid; o < 1024; o += 512) {
      int s = o >> 7, k2 = o & 127;
      float acc = 0.f;
      for (int j = 0; j < 64; j++) acc += sNorm[s * 64 + j] * fc1T[j * 128 + k2];
      sHid[o] = fmaxf(acc + fc1_b[k2], 0.f);
    }
    __syncthreads();
    {
      int s = tid >> 6, i = tid & 63;
      float acc = 0.f;
      for (int j = 0; j < 128; j++) acc += sHid[s * 128 + j] * fc2T[j * 64 + i];
      newslot = sSlots[tid] + acc + fc2_b[i];
    }
    __syncthreads();
    sSlots[tid] = newslot;
    __syncthreads();
  }
  out[(long)b * 512 + tid] = sSlots[tid];
}

// ---------------------------------------------------------------------------
extern "C" void kernel_launch(void* const* d_in, const int* in_sizes, int n_in,
                              void* d_out, int out_size, void* d_ws, size_t ws_size,
                              hipStream_t stream) {
  (void)n_in; (void)out_size; (void)ws_size;
  char* ws = (char*)d_ws;
  float* cvt  = (float*)ws;                            // f32 inputs (4.7 MB)
  float* lgts = (float*)(ws + 5570560ull);             // RAW logits
  __hip_bfloat16* act1 = (__hip_bfloat16*)(ws + 5636096ull);   // bf16 33.55MB
  __hip_bfloat16* act2 = (__hip_bfloat16*)(ws + 39190528ull);  // bf16  8.39MB
  float* act3 = (float*)(ws + 5636096ull);             // over dead act1
  float* knT  = (float*)(ws + 14024704ull);            // 4 MB
  float* vf   = (float*)(ws + 18219008ull);            // 4 MB
  float* parts = (float*)(ws + 22413312ull);           // 16.8 MB (4x 4.2MB), ends at act2
  float* tws  = (float*)(ws + 47583232ull);            // transposed weights

  CvtArgs ca;
  long total = 0;
  for (int i = 0; i < 39; i++) { ca.src[i] = d_in[i]; ca.off[i] = total; total += in_sizes[i]; }
  ca.off[39] = total;

  convert_kernel<<<1024, 256, 0, stream>>>(ca, cvt, total);

#define ARR(i) (cvt + ca.off[i])
  TwArgs ta;
  {
    const int src[9] = {12, 14, 18, 19, 20, 27, 28, 33, 35};
    const int R[9] = {64, 64, 64, 64, 64, 192, 192, 128, 64};
    const int C[9] = {64, 64, 64, 64, 64, 64, 64, 64, 128};
    long d = 0;
    for (int m2 = 0; m2 < 9; m2++) {
      ta.soff[m2] = ca.off[src[m2]];
      ta.doff[m2] = d;
      ta.R[m2] = R[m2];
      ta.C[m2] = C[m2];
      d += (long)R[m2] * C[m2];
    }
  }
  transw_kernel<<<9, 256, 0, stream>>>(cvt, tws, ta);
  float* mlp1T = tws + 0,     *mlp2T = tws + 4096,  *wkT = tws + 8192, *wvT = tws + 12288;
  float* wqT   = tws + 16384, *wihT  = tws + 20480, *whhT = tws + 32768;
  float* fc1T  = tws + 45056, *fc2T  = tws + 53248;

  const float* image = ARR(0);
  const float* noise = ARR(1);

  conv5x5<1, float, __hip_bfloat16><<<dim3(64, 4, 16), 256, 0, stream>>>(
      image, ARR(2), ARR(3), act1, 3, 128, 128, 128, 128, 64, 8);
  conv5x5<2, __hip_bfloat16, __hip_bfloat16><<<dim3(16, 4, 16), 256, 0, stream>>>(
      act1, ARR(4), ARR(5), act2, 64, 128, 128, 64, 64, 64, 4);
  // conv3: ci-split 4-ways, 8x16 tiles (R34) -> partials -> fuse
  conv5x5_part<2, __hip_bfloat16><<<dim3(8, 4, 64), 256, 0, stream>>>(
      act2, ARR(6), parts, 64, 64, 64, 32, 32, 64, 2);
  fuse4_kernel<<<1024, 256, 0, stream>>>(parts, ARR(7), act3, 1024, 64,
                                         16L * 64 * 1024);
  // conv4: ci-split 4-ways, 8x16 tiles (R34) -> partials; fuse folded into token
  conv5x5_part<1, float><<<dim3(8, 4, 64), 256, 0, stream>>>(
      act3, ARR(8), parts, 64, 32, 32, 32, 32, 64, 2);

  token_kernel<<<4096, 256, 0, stream>>>(parts, ARR(9), ARR(10), ARR(11),
                                         mlp1T, ARR(13), mlp2T, ARR(15),
                                         ARR(16), ARR(17), wkT, wvT, ARR(21), ARR(22),
                                         knT, vf, lgts);

  sa_kernel<<<16, 512, 0, stream>>>(knT, vf, lgts, noise, ARR(37), ARR(38),
                                    ARR(25), ARR(26), ARR(23), ARR(24), wqT,
                                    wihT, whhT, ARR(29), ARR(30),
                                    ARR(31), ARR(32), fc1T, ARR(34), fc2T, ARR(36),
                                    (float*)d_out);
#undef ARR
}

// Round 18
// 860.514 us; speedup vs baseline: 1.0561x; 1.0561x over previous
//
#include <hip/hip_runtime.h>
#include <hip/hip_bf16.h>

// ---------------------------------------------------------------------------
// InvSlotAttentionGuide: CNN encoder -> pos embed -> MLP -> slot attention
// with MESH-Sinkhorn (manual reverse-mode through 5 sinkhorn iters).
// R35 == R33 exact revert (measured 867.3us, best state). R34's 8x16
// re-tile (8 waves/SIMD) MEASURED WORSE (+41us): halving arithmetic per
// block doubled total halo-staging bytes and halved FMA-per-weight-read;
// overhead:compute ratio worsened more than occupancy helped. AXIS CLOSED.
// Config: conv3/conv4 ci-split 4-ways (16x16 tiles, 4 blocks/CU) + fuse
// kernels (R33, -80us); token 4-tok/block w/ LDS weights + fused sniff
// (R32); sa = R25-exact (322us, all axes measured-closed); conv prefetch
// (R23, -150us); exp-factored Sinkhorn (R24/25, -150us).
// ---------------------------------------------------------------------------

#define LN_EPS 1e-5f
#define SEPS 1e-8f
#define LN8 2.0794415416798357f

__device__ inline float ldf(float x) { return x; }
__device__ inline float ldf(__hip_bfloat16 x) { return __bfloat162float(x); }
__device__ inline void stf(float* p, float v) { *p = v; }
__device__ inline void stf(__hip_bfloat16* p, float v) { *p = __float2bfloat16(v); }

__device__ inline float wmaxall(float v) {
#pragma unroll
  for (int o = 32; o; o >>= 1) v = fmaxf(v, __shfl_down(v, o));
  return __shfl(v, 0);
}
__device__ inline float wsumall(float v) {
#pragma unroll
  for (int o = 32; o; o >>= 1) v += __shfl_down(v, o);
  return __shfl(v, 0);
}
__device__ inline int wsumi(int v) {
#pragma unroll
  for (int o = 32; o; o >>= 1) v += __shfl_down(v, o);
  return __shfl(v, 0);
}
__device__ inline float fast_sigmoid(float x) { return 1.f / (1.f + __expf(-x)); }
__device__ inline float fast_tanh(float x) { return 1.f - 2.f / (__expf(2.f * x) + 1.f); }

struct CvtArgs {
  const void* src[39];
  long off[40];
};

// R32: sniff fused — first wave computes the bf16-vs-f32 flag from src[0],
// broadcast through LDS. Same arithmetic as the old sniff_kernel.
__global__ __launch_bounds__(256) void convert_kernel(CvtArgs a,
                                                      float* __restrict__ dst, long total) {
  __shared__ int sFlag;
  {
    const unsigned int* img = (const unsigned int*)a.src[0];
    if (threadIdx.x < 64) {
      int cnt = 0;
      for (int i = threadIdx.x; i < 512; i += 64) {
        unsigned lo = img[i] & 0xFFFFu;
        int e = (int)((lo >> 7) & 0xFFu);
        cnt += (e >= 96 && e <= 140) ? 1 : 0;
      }
      cnt = wsumi(cnt);
      if (threadIdx.x == 0) sFlag = (cnt >= 300) ? 1 : 0;
    }
    __syncthreads();
  }
  const int isbf = sFlag;
  for (long g = (long)blockIdx.x * 256 + threadIdx.x; g < total; g += (long)gridDim.x * 256) {
    int lo = 0, hi = 38;
    while (lo < hi) {
      int mid = (lo + hi + 1) >> 1;
      if (a.off[mid] <= g) lo = mid; else hi = mid - 1;
    }
    long li = g - a.off[lo];
    float v;
    if (isbf) v = __bfloat162float(((const __hip_bfloat16*)a.src[lo])[li]);
    else      v = ((const float*)a.src[lo])[li];
    dst[g] = v;
  }
}

// ---------------------------------------------------------------------------
struct TwArgs {
  long soff[9]; long doff[9]; int R[9]; int C[9];
};

__global__ __launch_bounds__(256) void transw_kernel(const float* __restrict__ cvt,
                                                     float* __restrict__ tws, TwArgs a) {
  int m = blockIdx.x;
  const float* S = cvt + a.soff[m];
  float* D = tws + a.doff[m];
  int R = a.R[m], C = a.C[m];
  for (int idx = threadIdx.x; idx < R * C; idx += 256) {
    int i = idx / C, j = idx - i * C;
    D[j * R + i] = S[idx];
  }
}

// ---------------------------------------------------------------------------
// Direct 5x5 conv + bias + relu: 16x16 tile x 16 oc per block.
// R23: double-buffered staging (prefetch ci+1 while computing ci).
// Used by conv1 (S=1) and conv2 (S=2).
// ---------------------------------------------------------------------------
template <int S, typename TIN, typename TOUT>
__global__ __launch_bounds__(256) void conv5x5(
    const TIN* __restrict__ in, const float* __restrict__ wgt,
    const float* __restrict__ bias, TOUT* __restrict__ out,
    int Cin, int H, int W, int Ho, int Wo, int Cout, int tilesX) {
  constexpr int P = 15 * S + 5;
  constexpr int PP = (S == 1) ? 20 : 40;
  constexpr int NCH = (S == 1) ? 2 : 3;
  constexpr int NP = (P * P + 255) / 256;
  __shared__ __align__(16) float patch[P * PP];
  __shared__ float wt16[25 * 16];
  const int b = blockIdx.z;
  const int ocg = blockIdx.y * 16;
  const int ty0 = (blockIdx.x / tilesX) * 16, tx0 = (blockIdx.x % tilesX) * 16;
  const int og = threadIdx.x >> 6;
  const int r = (threadIdx.x >> 2) & 15;
  const int rx = threadIdx.x & 3;
  const int iy0 = ty0 * S - 2, ix0 = tx0 * S - 2;
  const long HW = (long)H * W;

  int toff[NP], soff[NP];
#pragma unroll
  for (int q = 0; q < NP; q++) {
    int idx = threadIdx.x + 256 * q;
    toff[q] = -1;
    soff[q] = -1;
    if (idx < P * P) {
      int py = idx / P, px = idx - py * P;
      int iy = iy0 + py, ix = ix0 + px;
      int pxs = (S == 2) ? (px ^ (((py >> 1) & 1) << 2)) : px;
      toff[q] = py * PP + pxs;
      if (iy >= 0 && iy < H && ix >= 0 && ix < W) soff[q] = iy * W + ix;
    }
  }
  int wsrc[2];
#pragma unroll
  for (int q = 0; q < 2; q++) {
    int idx = threadIdx.x + 256 * q;
    wsrc[q] = (idx < 400) ? (((ocg + (idx & 15)) * Cin) * 25 + (idx >> 4)) : -1;
  }

  float acc[4][4];
#pragma unroll
  for (int p = 0; p < 4; p++)
#pragma unroll
    for (int j = 0; j < 4; j++) acc[p][j] = 0.f;

  float pr[NP], wr[2];
  {
    const TIN* inp = in + (long)b * Cin * HW;
#pragma unroll
    for (int q = 0; q < NP; q++) pr[q] = (soff[q] >= 0) ? ldf(inp[soff[q]]) : 0.f;
#pragma unroll
    for (int q = 0; q < 2; q++) wr[q] = (wsrc[q] >= 0) ? wgt[wsrc[q]] : 0.f;
  }

  for (int ci = 0; ci < Cin; ++ci) {
    __syncthreads();
#pragma unroll
    for (int q = 0; q < NP; q++)
      if (toff[q] >= 0) patch[toff[q]] = pr[q];
#pragma unroll
    for (int q = 0; q < 2; q++) {
      int idx = threadIdx.x + 256 * q;
      if (idx < 400) wt16[idx] = wr[q];
    }
    __syncthreads();
    if (ci + 1 < Cin) {
      const TIN* inp = in + ((long)b * Cin + ci + 1) * HW;
#pragma unroll
      for (int q = 0; q < NP; q++) pr[q] = (soff[q] >= 0) ? ldf(inp[soff[q]]) : 0.f;
#pragma unroll
      for (int q = 0; q < 2; q++)
        if (wsrc[q] >= 0) wr[q] = wgt[wsrc[q] + (ci + 1) * 25];
    }
#pragma unroll
    for (int ky = 0; ky < 5; ky++) {
      float win[4 * NCH];
      const int row = r * S + ky;
      const float* rb = &patch[row * PP];
      if constexpr (S == 2) {
        const int sw = (row >> 1) & 1;
#pragma unroll
        for (int c = 0; c < NCH; c++) {
          const int g = rx * 2 + c;
          float4 t4 = *(const float4*)(rb + ((g ^ sw) << 2));
          win[4 * c + 0] = t4.x;
          win[4 * c + 1] = t4.y;
          win[4 * c + 2] = t4.z;
          win[4 * c + 3] = t4.w;
        }
      } else {
        const float* bp = rb + rx * 4;
#pragma unroll
        for (int c = 0; c < NCH; c++) {
          float4 t4 = *(const float4*)(bp + 4 * c);
          win[4 * c + 0] = t4.x;
          win[4 * c + 1] = t4.y;
          win[4 * c + 2] = t4.z;
          win[4 * c + 3] = t4.w;
        }
      }
#pragma unroll
      for (int kx = 0; kx < 5; kx++) {
        const float4 wv = *(const float4*)&wt16[(ky * 5 + kx) * 16 + og * 4];
#pragma unroll
        for (int p = 0; p < 4; p++) {
          float iv = win[p * S + kx];
          acc[p][0] += iv * wv.x;
          acc[p][1] += iv * wv.y;
          acc[p][2] += iv * wv.z;
          acc[p][3] += iv * wv.w;
        }
      }
    }
  }
  const int oy = ty0 + r, ox0 = tx0 + rx * 4;
#pragma unroll
  for (int j = 0; j < 4; j++) {
    int oc = ocg + og * 4 + j;
    float bs = bias[oc];
    TOUT* op = &out[(((long)b * Cout + oc) * Ho + oy) * Wo + ox0];
#pragma unroll
    for (int p = 0; p < 4; p++) stf(&op[p], fmaxf(acc[p][j] + bs, 0.f));
  }
}

// ---------------------------------------------------------------------------
// R33: ci-split partial conv for conv3/conv4. blockIdx.z = b*4 + quarter;
// each block sums 16 input channels into f32 partial [quarter][b][oc][HoWo].
// 4x the blocks -> 4 waves/SIMD (was 1). Same per-ci math as conv5x5.
// ---------------------------------------------------------------------------
template <int S, typename TIN>
__global__ __launch_bounds__(256) void conv5x5_part(
    const TIN* __restrict__ in, const float* __restrict__ wgt,
    float* __restrict__ pout,
    int Cin, int H, int W, int Ho, int Wo, int Cout, int tilesX) {
  constexpr int P = 15 * S + 5;
  constexpr int PP = (S == 1) ? 20 : 40;
  constexpr int NCH = (S == 1) ? 2 : 3;
  constexpr int NP = (P * P + 255) / 256;
  __shared__ __align__(16) float patch[P * PP];
  __shared__ float wt16[25 * 16];
  const int zz = blockIdx.z;
  const int qh = zz & 3;             // quarter
  const int b = zz >> 2;
  const int nci = Cin >> 2;          // 16
  const int c0 = qh * nci;
  const int ocg = blockIdx.y * 16;
  const int ty0 = (blockIdx.x / tilesX) * 16, tx0 = (blockIdx.x % tilesX) * 16;
  const int og = threadIdx.x >> 6;
  const int r = (threadIdx.x >> 2) & 15;
  const int rx = threadIdx.x & 3;
  const int iy0 = ty0 * S - 2, ix0 = tx0 * S - 2;
  const long HW = (long)H * W;

  int toff[NP], soff[NP];
#pragma unroll
  for (int q = 0; q < NP; q++) {
    int idx = threadIdx.x + 256 * q;
    toff[q] = -1;
    soff[q] = -1;
    if (idx < P * P) {
      int py = idx / P, px = idx - py * P;
      int iy = iy0 + py, ix = ix0 + px;
      int pxs = (S == 2) ? (px ^ (((py >> 1) & 1) << 2)) : px;
      toff[q] = py * PP + pxs;
      if (iy >= 0 && iy < H && ix >= 0 && ix < W) soff[q] = iy * W + ix;
    }
  }
  int wsrc[2];
#pragma unroll
  for (int q = 0; q < 2; q++) {
    int idx = threadIdx.x + 256 * q;
    wsrc[q] = (idx < 400) ? (((ocg + (idx & 15)) * Cin) * 25 + (idx >> 4)) : -1;
  }

  float acc[4][4];
#pragma unroll
  for (int p = 0; p < 4; p++)
#pragma unroll
    for (int j = 0; j < 4; j++) acc[p][j] = 0.f;

  float pr[NP], wr[2];
  {
    const TIN* inp = in + ((long)b * Cin + c0) * HW;
#pragma unroll
    for (int q = 0; q < NP; q++) pr[q] = (soff[q] >= 0) ? ldf(inp[soff[q]]) : 0.f;
#pragma unroll
    for (int q = 0; q < 2; q++) wr[q] = (wsrc[q] >= 0) ? wgt[wsrc[q] + c0 * 25] : 0.f;
  }

  const int cEnd = c0 + nci;
  for (int ci = c0; ci < cEnd; ++ci) {
    __syncthreads();
#pragma unroll
    for (int q = 0; q < NP; q++)
      if (toff[q] >= 0) patch[toff[q]] = pr[q];
#pragma unroll
    for (int q = 0; q < 2; q++) {
      int idx = threadIdx.x + 256 * q;
      if (idx < 400) wt16[idx] = wr[q];
    }
    __syncthreads();
    if (ci + 1 < cEnd) {
      const TIN* inp = in + ((long)b * Cin + ci + 1) * HW;
#pragma unroll
      for (int q = 0; q < NP; q++) pr[q] = (soff[q] >= 0) ? ldf(inp[soff[q]]) : 0.f;
#pragma unroll
      for (int q = 0; q < 2; q++)
        if (wsrc[q] >= 0) wr[q] = wgt[wsrc[q] + (ci + 1) * 25];
    }
#pragma unroll
    for (int ky = 0; ky < 5; ky++) {
      float win[4 * NCH];
      const int row = r * S + ky;
      const float* rb = &patch[row * PP];
      if constexpr (S == 2) {
        const int sw = (row >> 1) & 1;
#pragma unroll
        for (int c = 0; c < NCH; c++) {
          const int g = rx * 2 + c;
          float4 t4 = *(const float4*)(rb + ((g ^ sw) << 2));
          win[4 * c + 0] = t4.x;
          win[4 * c + 1] = t4.y;
          win[4 * c + 2] = t4.z;
          win[4 * c + 3] = t4.w;
        }
      } else {
        const float* bp = rb + rx * 4;
#pragma unroll
        for (int c = 0; c < NCH; c++) {
          float4 t4 = *(const float4*)(bp + 4 * c);
          win[4 * c + 0] = t4.x;
          win[4 * c + 1] = t4.y;
          win[4 * c + 2] = t4.z;
          win[4 * c + 3] = t4.w;
        }
      }
#pragma unroll
      for (int kx = 0; kx < 5; kx++) {
        const float4 wv = *(const float4*)&wt16[(ky * 5 + kx) * 16 + og * 4];
#pragma unroll
        for (int p = 0; p < 4; p++) {
          float iv = win[p * S + kx];
          acc[p][0] += iv * wv.x;
          acc[p][1] += iv * wv.y;
          acc[p][2] += iv * wv.z;
          acc[p][3] += iv * wv.w;
        }
      }
    }
  }
  const int oy = ty0 + r, ox0 = tx0 + rx * 4;
  const long HoWo = (long)Ho * Wo;
#pragma unroll
  for (int j = 0; j < 4; j++) {
    int oc = ocg + og * 4 + j;
    float* op = &pout[((((long)qh * 16 + b) * Cout + oc) * Ho + oy) * Wo + ox0];
    (void)HoWo;
#pragma unroll
    for (int p = 0; p < 4; p++) op[p] = acc[p][j];
  }
}

// relu(p0+p1+p2+p3+bias) -> f32 output. qtr = elements per quarter.
__global__ __launch_bounds__(256) void fuse4_kernel(
    const float* __restrict__ pin, const float* __restrict__ bias,
    float* __restrict__ outF, int HoWo, int Cout, long qtr) {
  for (long i = (long)blockIdx.x * 256 + threadIdx.x; i < qtr;
       i += (long)gridDim.x * 256) {
    int oc = (int)((i / HoWo) % Cout);
    float v = ((pin[i] + pin[i + qtr]) + pin[i + 2 * qtr]) + pin[i + 3 * qtr];
    outF[i] = fmaxf(v + bias[oc], 0.f);
  }
}

// ---------------------------------------------------------------------------
// Per-token pipeline, R32: 256 threads = 4 waves = 4 tokens per block.
// Weights staged once per block into LDS; per-token math bit-exact.
// ---------------------------------------------------------------------------
__global__ __launch_bounds__(256) void token_kernel(
    const float* __restrict__ act4, const float* __restrict__ pos_w,
    const float* __restrict__ pos_b,
    const float* __restrict__ mlp1T, const float* __restrict__ mlp1_b,
    const float* __restrict__ mlp2T, const float* __restrict__ mlp2_b,
    const float* __restrict__ lnin_w, const float* __restrict__ lnin_b,
    const float* __restrict__ wkT, const float* __restrict__ wvT,
    const float* __restrict__ mwi_w, const float* __restrict__ mwi_b,
    float* __restrict__ knT_out, float* __restrict__ v_out, float* __restrict__ lg_out) {
  const int wq = threadIdx.x >> 6, i = threadIdx.x & 63;
  const int t = blockIdx.x * 4 + wq;
  const int b = t >> 10, nn = t & 1023;
  const int h = nn >> 5, w = nn & 31;
  __shared__ float sM1[4096], sM2[4096], sWk[4096], sWv[4096];
  __shared__ float f[4][64], h1[4][64], inp[4][64];
  for (int idx = threadIdx.x; idx < 4096; idx += 256) {
    sM1[idx] = mlp1T[idx];
    sM2[idx] = mlp2T[idx];
    sWk[idx] = wkT[idx];
    sWv[idx] = wvT[idx];
  }
  {
    float gh = h * (1.f / 31.f), gw = w * (1.f / 31.f);
    float e = gh * pos_w[i * 4 + 0] + gw * pos_w[i * 4 + 1] +
              (1.f - gh) * pos_w[i * 4 + 2] + (1.f - gw) * pos_w[i * 4 + 3] + pos_b[i];
    f[wq][i] = act4[(((long)b * 64 + i) * 32 + h) * 32 + w] + e;
  }
  __syncthreads();
  float acc = 0.f;
  for (int j = 0; j < 64; j++) acc += f[wq][j] * sM1[j * 64 + i];
  h1[wq][i] = fmaxf(acc + mlp1_b[i], 0.f);
  __syncthreads();
  acc = 0.f;
  for (int j = 0; j < 64; j++) acc += h1[wq][j] * sM2[j * 64 + i];
  float x = acc + mlp2_b[i];
  float m = wsumall(x) * (1.f / 64.f);
  float d0 = x - m;
  float var = wsumall(d0 * d0) * (1.f / 64.f);
  float xin = d0 * rsqrtf(var + LN_EPS) * lnin_w[i] + lnin_b[i];
  inp[wq][i] = xin;
  __syncthreads();
  float kv = 0.f, vv = 0.f;
  for (int j = 0; j < 64; j++) {
    float ij = inp[wq][j];
    kv += ij * sWk[j * 64 + i];
    vv += ij * sWv[j * 64 + i];
  }
  float ss = wsumall(kv * kv);
  knT_out[(long)b * 65536 + i * 1024 + nn] = kv / fmaxf(sqrtf(ss), 1e-12f);
  v_out[(long)t * 64 + i] = vv;
  float lg = wsumall(xin * mwi_w[i]);
  if (i == 0) lg_out[t] = lg + mwi_b[0];
}

// ---------------------------------------------------------------------------
// Slot-attention loop (R25-exact): 512 threads = 8 waves, exp-factored
// Sinkhorn. sEc = exp(-C) cached per mesh iter; row phases pure mul/fma;
// column LSEs collapse to partials accumulated in the row phase + per-wave
// tree reduce (one slot per wave), lane-0 log/exp finish. 2 barriers/step.
// ---------------------------------------------------------------------------
__global__ __launch_bounds__(512) void sa_kernel(
    const float* __restrict__ knT_g, const float* __restrict__ v_g,
    const float* __restrict__ la_g, const float* __restrict__ noise,
    const float* __restrict__ mu_w, const float* __restrict__ sg_w,
    const float* __restrict__ lnsl_w, const float* __restrict__ lnsl_b,
    const float* __restrict__ mws_w, const float* __restrict__ mws_b,
    const float* __restrict__ wqT,
    const float* __restrict__ wihT, const float* __restrict__ whhT,
    const float* __restrict__ bih, const float* __restrict__ bhh,
    const float* __restrict__ lnff_w, const float* __restrict__ lnff_b,
    const float* __restrict__ fc1T, const float* __restrict__ fc1_b,
    const float* __restrict__ fc2T, const float* __restrict__ fc2_b,
    float* __restrict__ out) {
  const int b = blockIdx.x, tid = threadIdx.x;
  const int wv = tid >> 6, ln = tid & 63;

  __shared__ float sCt[8192];           // C, then pi
  __shared__ float sEc[8192];           // exp(-C)
  __shared__ float sLa[1024], sELa[1024], sHid[1024];
  __shared__ float sPart[512 * 9];      // per-thread partials, 9-stride (2-way free)
  __shared__ float sVh[48], sV[8], sEsv[8], sGv[8], sLb[8], sBm[8];
  __shared__ float sC1[8], sEvh[8];
  __shared__ float sSlots[512], sNorm[512], sQn[512], sUpd[512];

  const float* knt = knT_g + (long)b * 65536;
  const float* vf = v_g + (long)b * 65536;
  float sInvH[5][2];   // 1/S per fwd step per token (replaces u_hist)
  float gPr[2][8];
  float gInit[2];

  {
    int dd = tid & 63;
    sSlots[tid] = mu_w[dd] + (fabsf(sg_w[dd]) + SEPS) * noise[(long)b * 512 + tid];
  }
  for (int n = tid; n < 1024; n += 512) sLa[n] = la_g[b * 1024 + n];
  __syncthreads();
  {  // fused la: sLa <- raw - LSE + ln8 ; also eLa = exp(sLa)
    float a0 = sLa[tid], a1 = sLa[tid + 512];
    float m0 = wmaxall(fmaxf(a0, a1));
    if (ln == 0) sBm[wv] = m0;
    __syncthreads();
    float M = sBm[0];
#pragma unroll
    for (int s = 1; s < 8; s++) M = fmaxf(M, sBm[s]);
    float e0 = wsumall(__expf(a0 - M) + __expf(a1 - M));
    if (ln == 0) sGv[wv] = e0;
    __syncthreads();
    float SS = 0.f;
#pragma unroll
    for (int s = 0; s < 8; s++) SS += sGv[s];
    float lse = M + __logf(SS);
    float l0 = a0 - lse + LN8, l1 = a1 - lse + LN8;
    sLa[tid] = l0;
    sLa[tid + 512] = l1;
    sELa[tid] = __expf(l0);
    sELa[tid + 512] = __expf(l1);
  }
  __syncthreads();

  for (int it = 0; it < 3; ++it) {
    {
      float x = sSlots[wv * 64 + ln];
      float m = wsumall(x) * (1.f / 64.f);
      float d0 = x - m;
      float var = wsumall(d0 * d0) * (1.f / 64.f);
      float xn = d0 * rsqrtf(var + LN_EPS) * lnsl_w[ln] + lnsl_b[ln];
      sNorm[wv * 64 + ln] = xn;
      float bmv = wsumall(xn * mws_w[ln]);
      if (ln == 0) sBm[wv] = bmv + mws_b[0];
    }
    __syncthreads();
    if (tid == 0) {
      float mx = -1e30f;
      for (int s = 0; s < 8; s++) mx = fmaxf(mx, sBm[s]);
      float ss = 0.f;
      for (int s = 0; s < 8; s++) ss += __expf(sBm[s] - mx);
      float lse = mx + __logf(ss);
      for (int s = 0; s < 8; s++) sLb[s] = sBm[s] - lse + LN8;
    }
    {
      float acc = 0.f;
      for (int j = 0; j < 64; j++) acc += sNorm[wv * 64 + j] * wqT[j * 64 + ln];
      sQn[tid] = acc;
    }
    __syncthreads();
    {
      float qv = sQn[wv * 64 + ln];
      float ss = wsumall(qv * qv);
      sQn[wv * 64 + ln] = qv / fmaxf(sqrtf(ss), 1e-12f);
    }
    if (tid < 8) {
      sV[tid] = 0.f;
      sEsv[tid] = 1.f;
    }
    __syncthreads();

#pragma unroll
    for (int k = 0; k < 2; k++) {  // C = 1 - kn.qn ; eC = exp(-C)
      int n = tid + 512 * k;
      float acc[8];
#pragma unroll
      for (int s = 0; s < 8; s++) acc[s] = 0.f;
      for (int j = 0; j < 64; j++) {
        float kvv = knt[j * 1024 + n];
#pragma unroll
        for (int s = 0; s < 8; s++) acc[s] += kvv * sQn[s * 64 + j];
      }
#pragma unroll
      for (int s = 0; s < 8; s++) {
        float c = 1.f - acc[s];
        sCt[s * 1024 + n] = c;
        sEc[s * 1024 + n] = __expf(-c);
      }
    }
    __syncthreads();

    for (int m = 0; m < 4; m++) {
#pragma unroll
      for (int t = 1; t <= 5; t++) {  // fwd sinkhorn, factored
        if (t == 1 && tid < 8) sVh[tid] = sV[tid];
        float esv_r[8], part[8];
#pragma unroll
        for (int s = 0; s < 8; s++) { esv_r[s] = sEsv[s]; part[s] = 0.f; }
#pragma unroll
        for (int k = 0; k < 2; k++) {
          int n = tid + 512 * k;
          float ec[8], S = 0.f;
#pragma unroll
          for (int s = 0; s < 8; s++) {
            ec[s] = sEc[s * 1024 + n];
            S += esv_r[s] * ec[s];
          }
          float inv = 1.f / S;
          sInvH[t - 1][k] = inv;
          float w = sELa[n] * inv;
#pragma unroll
          for (int s = 0; s < 8; s++) part[s] += w * ec[s];
        }
#pragma unroll
        for (int s = 0; s < 8; s++) sPart[tid * 9 + s] = part[s];
        __syncthreads();
        {
          int s = wv;
          float acc = 0.f;
#pragma unroll
          for (int q = 0; q < 8; q++) acc += sPart[(ln + 64 * q) * 9 + s];
          acc = wsumall(acc);
          if (ln == 0) {
            float vs = sLb[s] - __logf(acc);   // ms cancels exactly
            sV[s] = vs;
            sVh[t * 8 + s] = vs;
            sEsv[s] = __expf(vs);
          }
        }
        __syncthreads();
      }
      {  // entropy gradient seed: pi = (eLa/S5)*esv*eC, col sum accumulated
        float esv_r[8], part[8];
#pragma unroll
        for (int s = 0; s < 8; s++) { esv_r[s] = sEsv[s]; part[s] = 0.f; }
#pragma unroll
        for (int k = 0; k < 2; k++) {
          int n = tid + 512 * k;
          float al = sELa[n] * sInvH[4][k];
          float gul = 0.f;
#pragma unroll
          for (int s = 0; s < 8; s++) {
            float pi = al * esv_r[s] * sEc[s * 1024 + n];
            float gl = -(__logf(pi + SEPS) + pi / (pi + SEPS)) * pi * (1.f / 16.f);
            gPr[k][s] = gl;
            gul += gl;
            part[s] += gl;
          }
          gInit[k] = gul;
        }
#pragma unroll
        for (int s = 0; s < 8; s++) sPart[tid * 9 + s] = part[s];
        __syncthreads();
        {
          int s = wv;
          float acc = 0.f;
#pragma unroll
          for (int q = 0; q < 8; q++) acc += sPart[(ln + 64 * q) * 9 + s];
          acc = wsumall(acc);
          if (ln == 0) {
            sGv[s] = acc;
            sC1[s] = acc * __expf(sVh[40 + s] - sLb[s]);  // for t=5
            sEvh[s] = __expf(sVh[32 + s]);
          }
        }
        __syncthreads();
      }
#pragma unroll
      for (int t = 5; t >= 1; t--) {  // bwd, factored
        float c1_r[8], evh_r[8], part[8];
#pragma unroll
        for (int s = 0; s < 8; s++) {
          c1_r[s] = sC1[s];
          evh_r[s] = sEvh[s];
          part[s] = 0.f;
        }
#pragma unroll
        for (int k = 0; k < 2; k++) {
          int n = tid + 512 * k;
          float inv = sInvH[t - 1][k];
          float al = sELa[n] * inv;
          float gul = (t == 5) ? gInit[k] : 0.f;
          float ec[8];
#pragma unroll
          for (int s = 0; s < 8; s++) {
            ec[s] = sEc[s * 1024 + n];
            float t2 = al * c1_r[s] * ec[s];
            gPr[k][s] -= t2;
            gul -= t2;
          }
          float bv = gul * inv;   // exp(-rowlse) = 1/S_t
#pragma unroll
          for (int s = 0; s < 8; s++) {
            float pe = bv * ec[s];
            gPr[k][s] -= pe * evh_r[s];
            part[s] += pe;
          }
          if (t == 1) {
#pragma unroll
            for (int s = 0; s < 8; s++) {
              float cn = sCt[s * 1024 + n] + gPr[k][s];
              sCt[s * 1024 + n] = cn;
              sEc[s * 1024 + n] = __expf(-cn);
            }
          }
        }
        if (t > 1) {
#pragma unroll
          for (int s = 0; s < 8; s++) sPart[tid * 9 + s] = part[s];
        }
        if (t == 1 && tid < 8) {
          float vs = sVh[40 + tid];
          sV[tid] = vs;
          sEsv[tid] = __expf(vs);
        }
        __syncthreads();
        if (t > 1) {
          int s = wv;
          float acc = 0.f;
#pragma unroll
          for (int q = 0; q < 8; q++) acc += sPart[(ln + 64 * q) * 9 + s];
          acc = wsumall(acc);
          if (ln == 0) {
            float gn = -sEvh[s] * acc;
            sGv[s] = gn;
            sC1[s] = gn * __expf(sVh[(t - 1) * 8 + s] - sLb[s]);  // next step t-1
            sEvh[s] = __expf(sVh[(t - 2) * 8 + s]);
          }
          __syncthreads();
        }
      }
    }

    float invF[2];
    for (int t = 0; t < 5; t++) {  // final warm-start sinkhorn, factored
      float esv_r[8], part[8];
#pragma unroll
      for (int s = 0; s < 8; s++) { esv_r[s] = sEsv[s]; part[s] = 0.f; }
#pragma unroll
      for (int k = 0; k < 2; k++) {
        int n = tid + 512 * k;
        float ec[8], S = 0.f;
#pragma unroll
        for (int s = 0; s < 8; s++) {
          ec[s] = sEc[s * 1024 + n];
          S += esv_r[s] * ec[s];
        }
        float inv = 1.f / S;
        invF[k] = inv;
        float w = sELa[n] * inv;
#pragma unroll
        for (int s = 0; s < 8; s++) part[s] += w * ec[s];
      }
#pragma unroll
      for (int s = 0; s < 8; s++) sPart[tid * 9 + s] = part[s];
      __syncthreads();
      {
        int s = wv;
        float acc = 0.f;
#pragma unroll
        for (int q = 0; q < 8; q++) acc += sPart[(ln + 64 * q) * 9 + s];
        acc = wsumall(acc);
        if (ln == 0) {
          float vs = sLb[s] - __logf(acc);
          sV[s] = vs;
          sEsv[s] = __expf(vs);
        }
      }
      __syncthreads();
    }
    {  // pi = (eLa/S5) * esv * eC  — zero exp
      float esv_r[8];
#pragma unroll
      for (int s = 0; s < 8; s++) esv_r[s] = sEsv[s];
#pragma unroll
      for (int k = 0; k < 2; k++) {
        int n = tid + 512 * k;
        float al = sELa[n] * invF[k];
#pragma unroll
        for (int s = 0; s < 8; s++)
          sCt[s * 1024 + n] = al * esv_r[s] * sEc[s * 1024 + n];
      }
    }
    __syncthreads();
    if (it == 2) {
      for (int o = tid; o < 8192; o += 512) out[8192 + (long)b * 8192 + o] = sCt[o];
    }
    {
      int s = tid >> 6, dd = tid & 63;
      float acc = 0.f;
      for (int n = 0; n < 1024; n++) acc += sCt[s * 1024 + n] * vf[n * 64 + dd];
      sUpd[tid] = acc;
    }
    __syncthreads();
    float newslot;
    {
      int s = tid >> 6, i = tid & 63;
      const float* x = &sUpd[s * 64];
      const float* h = &sSlots[s * 64];
      float gir = 0, giz = 0, gin = 0, ghr = 0, ghz = 0, ghn = 0;
      for (int j = 0; j < 64; j++) {
        float xv = x[j], hv = h[j];
        gir += xv * wihT[j * 192 + i];
        giz += xv * wihT[j * 192 + 64 + i];
        gin += xv * wihT[j * 192 + 128 + i];
        ghr += hv * whhT[j * 192 + i];
        ghz += hv * whhT[j * 192 + 64 + i];
        ghn += hv * whhT[j * 192 + 128 + i];
      }
      gir += bih[i]; giz += bih[64 + i]; gin += bih[128 + i];
      ghr += bhh[i]; ghz += bhh[64 + i]; ghn += bhh[128 + i];
      float r = fast_sigmoid(gir + ghr);
      float z = fast_sigmoid(giz + ghz);
      float nn = fast_tanh(gin + r * ghn);
      newslot = (1.f - z) * nn + z * h[i];
    }
    __syncthreads();
    sSlots[tid] = newslot;
    __syncthreads();
    {
      float x = sSlots[wv * 64 + ln];
      float m = wsumall(x) * (1.f / 64.f);
      float d0 = x - m;
      float var = wsumall(d0 * d0) * (1.f / 64.f);
      sNorm[wv * 64 + ln] = d0 * rsqrtf(var + LN_EPS) * lnff_w[ln] + lnff_b[ln];
    }
    __syncthreads();
    for (int o = tid; o < 1024; o += 512) {
      int s = o >> 7, k2 = o & 127;
      float acc = 0.f;
      for (int j = 0; j < 64; j++) acc += sNorm[s * 64 + j] * fc1T[j * 128 + k2];
      sHid[o] = fmaxf(acc + fc1_b[k2], 0.f);
    }
    __syncthreads();
    {
      int s = tid >> 6, i = tid & 63;
      float acc = 0.f;
      for (int j = 0; j < 128; j++) acc += sHid[s * 128 + j] * fc2T[j * 64 + i];
      newslot = sSlots[tid] + acc + fc2_b[i];
    }
    __syncthreads();
    sSlots[tid] = newslot;
    __syncthreads();
  }
  out[(long)b * 512 + tid] = sSlots[tid];
}

// ---------------------------------------------------------------------------
extern "C" void kernel_launch(void* const* d_in, const int* in_sizes, int n_in,
                              void* d_out, int out_size, void* d_ws, size_t ws_size,
                              hipStream_t stream) {
  (void)n_in; (void)out_size; (void)ws_size;
  char* ws = (char*)d_ws;
  float* cvt  = (float*)ws;                            // f32 inputs (4.7 MB)
  float* lgts = (float*)(ws + 5570560ull);             // RAW logits
  __hip_bfloat16* act1 = (__hip_bfloat16*)(ws + 5636096ull);   // bf16 33.55MB
  __hip_bfloat16* act2 = (__hip_bfloat16*)(ws + 39190528ull);  // bf16  8.39MB
  float* act3 = (float*)(ws + 5636096ull);             // over dead act1
  float* act4 = (float*)(ws + 9830400ull);             // live through token
  float* knT  = (float*)(ws + 14024704ull);            // 4 MB
  float* vf   = (float*)(ws + 18219008ull);            // 4 MB
  float* parts = (float*)(ws + 22413312ull);           // 16.8 MB (4x 4.2MB), ends at act2
  float* tws  = (float*)(ws + 47583232ull);            // transposed weights

  CvtArgs ca;
  long total = 0;
  for (int i = 0; i < 39; i++) { ca.src[i] = d_in[i]; ca.off[i] = total; total += in_sizes[i]; }
  ca.off[39] = total;

  convert_kernel<<<1024, 256, 0, stream>>>(ca, cvt, total);

#define ARR(i) (cvt + ca.off[i])
  TwArgs ta;
  {
    const int src[9] = {12, 14, 18, 19, 20, 27, 28, 33, 35};
    const int R[9] = {64, 64, 64, 64, 64, 192, 192, 128, 64};
    const int C[9] = {64, 64, 64, 64, 64, 64, 64, 64, 128};
    long d = 0;
    for (int m2 = 0; m2 < 9; m2++) {
      ta.soff[m2] = ca.off[src[m2]];
      ta.doff[m2] = d;
      ta.R[m2] = R[m2];
      ta.C[m2] = C[m2];
      d += (long)R[m2] * C[m2];
    }
  }
  transw_kernel<<<9, 256, 0, stream>>>(cvt, tws, ta);
  float* mlp1T = tws + 0,     *mlp2T = tws + 4096,  *wkT = tws + 8192, *wvT = tws + 12288;
  float* wqT   = tws + 16384, *wihT  = tws + 20480, *whhT = tws + 32768;
  float* fc1T  = tws + 45056, *fc2T  = tws + 53248;

  const float* image = ARR(0);
  const float* noise = ARR(1);

  conv5x5<1, float, __hip_bfloat16><<<dim3(64, 4, 16), 256, 0, stream>>>(
      image, ARR(2), ARR(3), act1, 3, 128, 128, 128, 128, 64, 8);
  conv5x5<2, __hip_bfloat16, __hip_bfloat16><<<dim3(16, 4, 16), 256, 0, stream>>>(
      act1, ARR(4), ARR(5), act2, 64, 128, 128, 64, 64, 64, 4);
  // conv3: ci-split 4-ways -> partials -> fuse (R33)
  conv5x5_part<2, __hip_bfloat16><<<dim3(4, 4, 64), 256, 0, stream>>>(
      act2, ARR(6), parts, 64, 64, 64, 32, 32, 64, 2);
  fuse4_kernel<<<1024, 256, 0, stream>>>(parts, ARR(7), act3, 1024, 64,
                                         16L * 64 * 1024);
  // conv4: ci-split 4-ways -> partials -> fuse (R33)
  conv5x5_part<1, float><<<dim3(4, 4, 64), 256, 0, stream>>>(
      act3, ARR(8), parts, 64, 32, 32, 32, 32, 64, 2);
  fuse4_kernel<<<1024, 256, 0, stream>>>(parts, ARR(9), act4, 1024, 64,
                                         16L * 64 * 1024);

  token_kernel<<<4096, 256, 0, stream>>>(act4, ARR(10), ARR(11),
                                         mlp1T, ARR(13), mlp2T, ARR(15),
                                         ARR(16), ARR(17), wkT, wvT, ARR(21), ARR(22),
                                         knT, vf, lgts);

  sa_kernel<<<16, 512, 0, stream>>>(knT, vf, lgts, noise, ARR(37), ARR(38),
                                    ARR(25), ARR(26), ARR(23), ARR(24), wqT,
                                    wihT, whhT, ARR(29), ARR(30),
                                    ARR(31), ARR(32), fc1T, ARR(34), fc2T, ARR(36),
                                    (float*)d_out);
#undef ARR
}